// Round 1
// baseline (395.113 us; speedup 1.0000x reference)
//
#include <hip/hip_runtime.h>
#include <cstddef>
#include <cstdint>

// Problem constants (from reference)
#define B_ 64
#define T_ 2000
#define L_ 400
#define M_ 80
#define EPSF 1e-8f
#define LOG_EPSF -18.420680743952367f   // logf(1e-8)
// GLOBAL_STEP=0 -> progress=0 -> sigma = clip(Lb*0.05, 3, 10)

// Partial-array sizes (two-stage deterministic reduction, no atomics)
#define NA 1024   // mel blocks
#define NB 128    // gate blocks
#define NC 2048   // attn blocks

__device__ inline float waveReduce(float v) {
#pragma unroll
  for (int m = 32; m >= 1; m >>= 1) v += __shfl_xor(v, m, 64);
  return v;
}

// ---------------- mel L1 loss (masked) ----------------
__global__ __launch_bounds__(256) void mel_kernel(
    const float4* __restrict__ mo, const float4* __restrict__ mp,
    const float4* __restrict__ mt, const int* __restrict__ mel_lengths,
    double* __restrict__ partial) {
  const int N4 = B_ * T_ * M_ / 4;
  float acc = 0.f;
  const int stride = gridDim.x * blockDim.x;
  for (int i = blockIdx.x * blockDim.x + threadIdx.x; i < N4; i += stride) {
    int row = i / (M_ / 4);        // (b*T + t); M%4==0 so the 4 elems share a row
    int b = row / T_;
    int t = row - b * T_;
    if (t < mel_lengths[b]) {
      float4 a = mo[i], c = mp[i], d = mt[i];
      acc += fabsf(a.x - d.x) + fabsf(a.y - d.y) + fabsf(a.z - d.z) + fabsf(a.w - d.w);
      acc += fabsf(c.x - d.x) + fabsf(c.y - d.y) + fabsf(c.z - d.z) + fabsf(c.w - d.w);
    }
  }
  float w = waveReduce(acc);
  __shared__ double sh[4];
  int lane = threadIdx.x & 63, wid = threadIdx.x >> 6;
  if (lane == 0) sh[wid] = (double)w;
  __syncthreads();
  if (threadIdx.x == 0) partial[blockIdx.x] = sh[0] + sh[1] + sh[2] + sh[3];
}

// ---------------- gate BCE-with-logits ----------------
__global__ __launch_bounds__(256) void gate_kernel(
    const float* __restrict__ x, const float* __restrict__ zt,
    double* __restrict__ partial) {
  float acc = 0.f;
  const int stride = gridDim.x * blockDim.x;
  for (int i = blockIdx.x * blockDim.x + threadIdx.x; i < B_ * T_; i += stride) {
    float xv = x[i], z = zt[i];
    acc += fmaxf(xv, 0.f) - xv * z + log1pf(expf(-fabsf(xv)));
  }
  float w = waveReduce(acc);
  __shared__ double sh[4];
  int lane = threadIdx.x & 63, wid = threadIdx.x >> 6;
  if (lane == 0) sh[wid] = (double)w;
  __syncthreads();
  if (threadIdx.x == 0) partial[blockIdx.x] = sh[0] + sh[1] + sh[2] + sh[3];
}

// ---------------- attention KL + entropy ----------------
// One wave per (b,t) pair; lanes cover L=400 in 7 unrolled steps.
// Diagonal target recomputed analytically: g = exp(-0.5 z^2) masked to l<Lb.
// log(max(target,EPS)) = max(logg - log(S+eps), logEPS) since log is monotone.
__global__ __launch_bounds__(256) void attn_kernel(
    const float* __restrict__ align, const int* __restrict__ text_lengths,
    double* __restrict__ klP, double* __restrict__ entP) {
  const int lane = threadIdx.x & 63;
  const int wib = threadIdx.x >> 6;
  const int waveId = blockIdx.x * 4 + wib;
  const int numWaves = gridDim.x * 4;
  float kl_acc = 0.f, ent_acc = 0.f;
  for (int p = waveId; p < B_ * T_; p += numWaves) {
    int b = p / T_;
    int t = p - b * T_;
    int Lb = text_lengths[b];
    float sigma = fminf(fmaxf((float)Lb * 0.05f, 3.0f), 10.0f);  // progress = 0
    float invsig = 1.0f / sigma;
    int epi = t * Lb / T_;           // int floor-div, matches jnp // for nonneg
    int lim = Lb - 1;
    if (epi > lim) epi = lim;
    float ep = (float)epi;
    const float* row = align + (size_t)p * L_;
    float g[7], lp[7], ee[7];
    float S = 0.f;
#pragma unroll
    for (int k = 0; k < 7; ++k) {
      int l = lane + 64 * k;
      g[k] = 0.f; lp[k] = 0.f; ee[k] = 0.f;
      if (l < L_) {
        float a = row[l];
        float as = fmaxf(a, EPSF);
        float lpv = logf(as);
        lp[k] = lpv;
        ent_acc -= as * lpv;         // entropy sums over all l (no mask)
        float z = ((float)l - ep) * invsig;
        float e = -0.5f * z * z;
        ee[k] = e;
        float gv = (l < Lb) ? expf(e) : 0.f;
        g[k] = gv;
        S += gv;
      }
    }
    S = waveReduce(S);
    float Se = S + EPSF;
    float inv = 1.0f / Se;
    float logSe = logf(Se);
#pragma unroll
    for (int k = 0; k < 7; ++k) {
      int l = lane + 64 * k;
      if (l < L_ && g[k] > 0.f) {
        float tgt = g[k] * inv;
        float lt = fmaxf(ee[k] - logSe, LOG_EPSF);
        kl_acc += tgt * (lt - lp[k]);
      }
    }
  }
  float klw = waveReduce(kl_acc);
  float entw = waveReduce(ent_acc);
  __shared__ double skl[4], sent[4];
  if (lane == 0) { skl[wib] = (double)klw; sent[wib] = (double)entw; }
  __syncthreads();
  if (threadIdx.x == 0) {
    klP[blockIdx.x] = skl[0] + skl[1] + skl[2] + skl[3];
    entP[blockIdx.x] = sent[0] + sent[1] + sent[2] + sent[3];
  }
}

// ---------------- finalize ----------------
__device__ double segSum(const double* __restrict__ p, int n, double* sh) {
  double a = 0.0;
  for (int i = threadIdx.x; i < n; i += 256) a += p[i];
  sh[threadIdx.x] = a;
  __syncthreads();
  for (int s = 128; s > 0; s >>= 1) {
    if ((int)threadIdx.x < s) sh[threadIdx.x] += sh[threadIdx.x + s];
    __syncthreads();
  }
  double r = sh[0];
  __syncthreads();
  return r;
}

__global__ __launch_bounds__(256) void finalize_kernel(
    const double* __restrict__ ws, const int* __restrict__ mel_lengths,
    float* __restrict__ out) {
  __shared__ double sh[256];
  double mel_sum  = segSum(ws, NA, sh);
  double gate_sum = segSum(ws + NA, NB, sh);
  double kl_sum   = segSum(ws + NA + NB, NC, sh);
  double ent_sum  = segSum(ws + NA + NB + NC, NC, sh);
  if (threadIdx.x == 0) {
    long nv = 0;
    for (int b = 0; b < B_; ++b) nv += mel_lengths[b];
    double n_valid = (double)nv * (double)M_;
    float loss_mel  = (float)(mel_sum / n_valid);
    float loss_gate = (float)(gate_sum / (double)(B_ * T_));
    float kl  = (float)(kl_sum / (double)(B_ * T_));
    kl = fminf(kl, 150.0f);
    float ent = (float)(ent_sum / (double)(B_ * T_));
    float ratio = fmaxf(ent / 3.5f, 0.0f);
    float weight = (ent <= 3.5f) ? fmaxf(0.2f, 1.0f * ratio) : 1.0f;
    out[0] = loss_mel + loss_gate + weight * kl;
    out[1] = loss_mel;
    out[2] = loss_gate;
    out[3] = kl;
  }
}

extern "C" void kernel_launch(void* const* d_in, const int* in_sizes, int n_in,
                              void* d_out, int out_size, void* d_ws, size_t ws_size,
                              hipStream_t stream) {
  const float* mel_out_postnet = (const float*)d_in[0];
  const float* mel_out         = (const float*)d_in[1];
  const float* gate_out        = (const float*)d_in[2];
  const float* alignments     = (const float*)d_in[3];
  const float* mel_target      = (const float*)d_in[4];
  const float* gate_target     = (const float*)d_in[5];
  const int*   mel_lengths     = (const int*)d_in[6];
  const int*   text_lengths    = (const int*)d_in[7];
  float* out = (float*)d_out;
  double* ws = (double*)d_ws;

  double* melP  = ws;
  double* gateP = ws + NA;
  double* klP   = ws + NA + NB;
  double* entP  = ws + NA + NB + NC;

  mel_kernel<<<dim3(NA), dim3(256), 0, stream>>>(
      (const float4*)mel_out, (const float4*)mel_out_postnet,
      (const float4*)mel_target, mel_lengths, melP);
  gate_kernel<<<dim3(NB), dim3(256), 0, stream>>>(gate_out, gate_target, gateP);
  attn_kernel<<<dim3(NC), dim3(256), 0, stream>>>(alignments, text_lengths, klP, entP);
  finalize_kernel<<<dim3(1), dim3(256), 0, stream>>>(ws, mel_lengths, out);
}

// Round 2
// 389.850 us; speedup vs baseline: 1.0135x; 1.0135x over previous
//
#include <hip/hip_runtime.h>
#include <cstddef>
#include <cstdint>

// Problem constants (from reference)
#define B_ 64
#define T_ 2000
#define L_ 400
#define M_ 80
#define EPSF 1e-8f
#define LOG_EPSF -18.420680743952367f   // logf(1e-8)
// GLOBAL_STEP=0 -> progress=0 -> sigma = clip(Lb*0.05, 3, 10)

#define NBLK 2048   // fused-kernel grid; each block emits 4 double partials

__device__ inline float waveReduce(float v) {
#pragma unroll
  for (int m = 32; m >= 1; m >>= 1) v += __shfl_xor(v, m, 64);
  return v;
}

// One kernel: every block does a grid-stride slice of mel L1, gate BCE, and
// attention KL+entropy, so HBM-streaming (mel) and transcendental-heavy (attn)
// work co-schedule on every CU. 4 double partials per block -> ws.
__global__ __launch_bounds__(256) void fused_kernel(
    const float4* __restrict__ mo, const float4* __restrict__ mp,
    const float4* __restrict__ mt, const float* __restrict__ gx,
    const float* __restrict__ gz, const float* __restrict__ align,
    const int* __restrict__ mel_lengths, const int* __restrict__ text_lengths,
    double* __restrict__ ws) {
  const int tid = blockIdx.x * 256 + threadIdx.x;
  const int nthreads = NBLK * 256;

  // ---- mel L1 (masked) ----
  float mel_acc = 0.f;
  const int N4 = B_ * T_ * (M_ / 4);
  for (int i = tid; i < N4; i += nthreads) {
    int row = i / (M_ / 4);        // (b*T + t); the 4 packed elems share a row
    int b = row / T_;
    int t = row - b * T_;
    if (t < mel_lengths[b]) {
      float4 a = mo[i], c = mp[i], d = mt[i];
      mel_acc += fabsf(a.x - d.x) + fabsf(a.y - d.y) + fabsf(a.z - d.z) + fabsf(a.w - d.w)
               + fabsf(c.x - d.x) + fabsf(c.y - d.y) + fabsf(c.z - d.z) + fabsf(c.w - d.w);
    }
  }

  // ---- gate BCE-with-logits ----
  float gate_acc = 0.f;
  for (int i = tid; i < B_ * T_; i += nthreads) {
    float xv = gx[i], z = gz[i];
    gate_acc += fmaxf(xv, 0.f) - xv * z + log1pf(__expf(-fabsf(xv)));
  }

  // ---- attention KL + entropy: one wave per (b,t) row ----
  const int lane = threadIdx.x & 63;
  const int wib = threadIdx.x >> 6;
  const int waveId = blockIdx.x * 4 + wib;
  const int numWaves = NBLK * 4;
  float kl_acc = 0.f, ent_acc = 0.f;
  for (int p = waveId; p < B_ * T_; p += numWaves) {
    int b = p / T_;
    int t = p - b * T_;
    int Lb = text_lengths[b];
    float sigma = fminf(fmaxf((float)Lb * 0.05f, 3.0f), 10.0f);  // progress = 0
    float invsig = 1.0f / sigma;
    int epi = t * Lb / T_;           // floor-div, nonneg -> matches jnp //
    int lim = Lb - 1;
    if (epi > lim) epi = lim;
    float ep = (float)epi;
    const float* row = align + (size_t)p * L_;
    float g[7], lp[7], ee[7];
    float S = 0.f;
#pragma unroll
    for (int k = 0; k < 7; ++k) {
      int l = lane + 64 * k;
      g[k] = 0.f; lp[k] = 0.f; ee[k] = 0.f;
      if (l < L_) {
        float a = row[l];
        float as = fmaxf(a, EPSF);
        float lpv = __logf(as);
        lp[k] = lpv;
        ent_acc -= as * lpv;         // entropy sums over all l (no mask)
        float z = ((float)l - ep) * invsig;
        float e = -0.5f * z * z;
        ee[k] = e;
        float gv = (l < Lb) ? __expf(e) : 0.f;
        g[k] = gv;
        S += gv;
      }
    }
    S = waveReduce(S);
    float Se = S + EPSF;
    float inv = 1.0f / Se;
    float logSe = __logf(Se);
#pragma unroll
    for (int k = 0; k < 7; ++k) {
      int l = lane + 64 * k;
      if (l < L_ && g[k] > 0.f) {
        float tgt = g[k] * inv;
        // log(max(target,EPS)) = max(log g - log(S+eps), log EPS), log monotone
        float lt = fmaxf(ee[k] - logSe, LOG_EPSF);
        kl_acc += tgt * (lt - lp[k]);
      }
    }
  }

  // ---- block reduction of all 4 quantities ----
  float w0 = waveReduce(mel_acc);
  float w1 = waveReduce(gate_acc);
  float w2 = waveReduce(kl_acc);
  float w3 = waveReduce(ent_acc);
  __shared__ double sh[4][4];
  if (lane == 0) {
    sh[wib][0] = (double)w0; sh[wib][1] = (double)w1;
    sh[wib][2] = (double)w2; sh[wib][3] = (double)w3;
  }
  __syncthreads();
  if (threadIdx.x == 0) {
    ws[blockIdx.x]            = sh[0][0] + sh[1][0] + sh[2][0] + sh[3][0];
    ws[NBLK + blockIdx.x]     = sh[0][1] + sh[1][1] + sh[2][1] + sh[3][1];
    ws[2 * NBLK + blockIdx.x] = sh[0][2] + sh[1][2] + sh[2][2] + sh[3][2];
    ws[3 * NBLK + blockIdx.x] = sh[0][3] + sh[1][3] + sh[2][3] + sh[3][3];
  }
}

// ---------------- finalize ----------------
__device__ double segSum(const double* __restrict__ p, int n, double* sh) {
  double a = 0.0;
  for (int i = threadIdx.x; i < n; i += 256) a += p[i];
  sh[threadIdx.x] = a;
  __syncthreads();
  for (int s = 128; s > 0; s >>= 1) {
    if ((int)threadIdx.x < s) sh[threadIdx.x] += sh[threadIdx.x + s];
    __syncthreads();
  }
  double r = sh[0];
  __syncthreads();
  return r;
}

__global__ __launch_bounds__(256) void finalize_kernel(
    const double* __restrict__ ws, const int* __restrict__ mel_lengths,
    float* __restrict__ out) {
  __shared__ double sh[256];
  double mel_sum  = segSum(ws, NBLK, sh);
  double gate_sum = segSum(ws + NBLK, NBLK, sh);
  double kl_sum   = segSum(ws + 2 * NBLK, NBLK, sh);
  double ent_sum  = segSum(ws + 3 * NBLK, NBLK, sh);
  if (threadIdx.x == 0) {
    long nv = 0;
    for (int b = 0; b < B_; ++b) nv += mel_lengths[b];
    double n_valid = (double)nv * (double)M_;
    float loss_mel  = (float)(mel_sum / n_valid);
    float loss_gate = (float)(gate_sum / (double)(B_ * T_));
    float kl  = (float)(kl_sum / (double)(B_ * T_));
    kl = fminf(kl, 150.0f);
    float ent = (float)(ent_sum / (double)(B_ * T_));
    float ratio = fmaxf(ent / 3.5f, 0.0f);
    float weight = (ent <= 3.5f) ? fmaxf(0.2f, 1.0f * ratio) : 1.0f;
    out[0] = loss_mel + loss_gate + weight * kl;
    out[1] = loss_mel;
    out[2] = loss_gate;
    out[3] = kl;
  }
}

extern "C" void kernel_launch(void* const* d_in, const int* in_sizes, int n_in,
                              void* d_out, int out_size, void* d_ws, size_t ws_size,
                              hipStream_t stream) {
  const float* mel_out_postnet = (const float*)d_in[0];
  const float* mel_out         = (const float*)d_in[1];
  const float* gate_out        = (const float*)d_in[2];
  const float* alignments      = (const float*)d_in[3];
  const float* mel_target      = (const float*)d_in[4];
  const float* gate_target     = (const float*)d_in[5];
  const int*   mel_lengths     = (const int*)d_in[6];
  const int*   text_lengths    = (const int*)d_in[7];
  float* out = (float*)d_out;
  double* ws = (double*)d_ws;

  fused_kernel<<<dim3(NBLK), dim3(256), 0, stream>>>(
      (const float4*)mel_out, (const float4*)mel_out_postnet,
      (const float4*)mel_target, gate_out, gate_target,
      alignments, mel_lengths, text_lengths, ws);
  finalize_kernel<<<dim3(1), dim3(256), 0, stream>>>(ws, mel_lengths, out);
}